// Round 5
// baseline (677.145 us; speedup 1.0000x reference)
//
#include <hip/hip_runtime.h>
#include <stdint.h>

// Problem constants
#define S_LEN 2048
#define NH    24
#define HD    128
#define HID   3072    // NH*HD
#define IPS   512
#define IPD   1152

using f16   = __fp16;
using f16x4 = __fp16 __attribute__((ext_vector_type(4)));
using f16x8 = __fp16 __attribute__((ext_vector_type(8)));
using f32x4 = float  __attribute__((ext_vector_type(4)));
using f32x16 = float __attribute__((ext_vector_type(16)));

// ---------------------------------------------------------------------------
// async global->LDS, 16B per lane. LDS dest is wave-uniform base + lane*16.
__device__ __forceinline__ void glds16(const f16* g, f16* l) {
  __builtin_amdgcn_global_load_lds((const __attribute__((address_space(1))) void*)g,
                                   (__attribute__((address_space(3))) void*)l,
                                   16, 0, 0);
}

// ---------------------------------------------------------------------------
// one cast kernel for all 8 fp32->fp16 conversions
struct CastArgs { const float* src[8]; f16* dst[8]; long n4[8]; };

__global__ void k_cvt_all(CastArgs a, long total4) {
  long i = blockIdx.x * 256L + threadIdx.x;
  if (i >= total4) return;
  long r = i; int s = 0;
  while (r >= a.n4[s]) { r -= a.n4[s]; s++; }
  float4 v = ((const float4*)a.src[s])[r];
  f16x4 o;
  o.x = (f16)v.x; o.y = (f16)v.y; o.z = (f16)v.z; o.w = (f16)v.w;
  ((f16x4*)a.dst[s])[r] = o;
}

// ---------------------------------------------------------------------------
// Merged projection GEMM, XCD-grouped 1-D grid (1344 blocks).
// Work item (x=n-tile, y=m-tile, z=weight):
//  z=0: q   = hs @ Wq^T + bq    z=1: k = hs @ Wk^T + bk   z=2: v = hs @ Wv^T+bv
//  z=3: kip = ip @ Wkip^T+bkip  z=4: vip = ip @ Wvip^T + bvip  (y<4)
// Groups of 24 blocks sharing one A-row-panel (same y,z) are mapped to ids
// congruent mod 8 -> same XCD -> A-panel stays L2-resident (768 KB << 4 MB).
// Bijection: 1344 = 8 xcd * 24 x * 7 ghi; g = ghi*8+xcd in [0,56) -> (z,y).
// Body: 128x128 tile, BK=64, 4 waves, 32x32x16 MFMA, XOR-chunk LDS swizzle.
struct ProjArgs {
  const f16 *A0, *A1;
  const f16 *Wq, *Wk, *Wv, *Wkip, *Wvip;
  const float *bq, *bk, *bv, *bkip, *bvip;
  f16 *q, *k, *v, *kip, *vip;
};

__global__ __launch_bounds__(256) void k_gemm_proj(ProjArgs pa) {
  // --- XCD-grouping remap ---
  const int L    = blockIdx.x;        // 0..1343
  const int xcd  = L & 7;
  const int slot = L >> 3;            // 0..167
  const int xj   = slot % 24;         // n-tile
  const int ghi  = slot / 24;         // 0..6
  const int g    = ghi * 8 + xcd;     // 0..55 group = (z, m-tile)
  int z, ybm;
  if (g < 48) { z = g >> 4; ybm = g & 15; }
  else        { int r = g - 48; z = 3 + (r >> 2); ybm = r & 3; }

  const f16* A; const f16* B; const float* bias; f16* C; int K;
  if (z == 0)      { A = pa.A0; B = pa.Wq;   bias = pa.bq;   C = pa.q;   K = 3072; }
  else if (z == 1) { A = pa.A0; B = pa.Wk;   bias = pa.bk;   C = pa.k;   K = 3072; }
  else if (z == 2) { A = pa.A0; B = pa.Wv;   bias = pa.bv;   C = pa.v;   K = 3072; }
  else if (z == 3) { A = pa.A1; B = pa.Wkip; bias = pa.bkip; C = pa.kip; K = 1152; }
  else             { A = pa.A1; B = pa.Wvip; bias = pa.bvip; C = pa.vip; K = 1152; }

  __shared__ f16 As[128 * 64];
  __shared__ f16 Bs[128 * 64];

  const int tid = threadIdx.x;
  const int w   = tid >> 6, l = tid & 63;
  const int l31 = l & 31, hi = l >> 5;
  const int bm = ybm * 128, bn = xj * 128;
  const int wm = (w >> 1) * 64,    wn = (w & 1) * 64;

  f32x16 acc[2][2] = {};

  const int r0   = w * 32;
  const int srow = l >> 3;
  const int gch  = (l & 7) ^ (srow & 7);
  const f16* Ag = A + (long)(bm + r0 + srow) * K + gch * 8;
  const f16* Bg = B + (long)(bn + r0 + srow) * K + gch * 8;
  f16* lA = &As[r0 * 64];
  f16* lB = &Bs[r0 * 64];
  const long rs8 = 8L * K;
  const int swz = l & 7;

  for (int k0 = 0; k0 < K; k0 += 64) {
#pragma unroll
    for (int g2 = 0; g2 < 4; g2++) {
      glds16(Ag + g2 * rs8 + k0, lA + g2 * 512);
      glds16(Bg + g2 * rs8 + k0, lB + g2 * 512);
    }
    __syncthreads();

#pragma unroll
    for (int ks = 0; ks < 4; ks++) {
      const int pos = ((ks * 2 + hi) ^ swz) * 8;
      f16x8 af[2], bf[2];
#pragma unroll
      for (int mi = 0; mi < 2; mi++)
        af[mi] = *(const f16x8*)&As[(wm + mi * 32 + l31) * 64 + pos];
#pragma unroll
      for (int nj = 0; nj < 2; nj++)
        bf[nj] = *(const f16x8*)&Bs[(wn + nj * 32 + l31) * 64 + pos];
#pragma unroll
      for (int mi = 0; mi < 2; mi++)
#pragma unroll
        for (int nj = 0; nj < 2; nj++)
          acc[mi][nj] = __builtin_amdgcn_mfma_f32_32x32x16_f16(af[mi], bf[nj], acc[mi][nj], 0, 0, 0);
    }
    __syncthreads();
  }

  // epilogue: C/D layout col=lane&31, row=(reg&3)+8*(reg>>2)+4*(lane>>5)
#pragma unroll
  for (int mi = 0; mi < 2; mi++)
#pragma unroll
    for (int nj = 0; nj < 2; nj++) {
      const int col = bn + wn + nj * 32 + l31;
      const float bvv = bias[col];
      const int rowb = bm + wm + mi * 32 + 4 * hi;
#pragma unroll
      for (int reg = 0; reg < 16; reg++) {
        const int row = rowb + (reg & 3) + 8 * (reg >> 2);
        C[(long)row * HID + col] = (f16)(acc[mi][nj][reg] + bvv);
      }
    }
}

// ---------------------------------------------------------------------------
// NT GEMM (out-projection): C[M,N] = A[M,K] @ B[N,K]^T + bias, fp32 out.
__global__ __launch_bounds__(256) void k_gemm_nt(
    const f16* __restrict__ A, const f16* __restrict__ B,
    const float* __restrict__ bias, float* __restrict__ Cv,
    int M, int N, int K)
{
  __shared__ f16 As[128 * 64];
  __shared__ f16 Bs[128 * 64];

  const int tid = threadIdx.x;
  const int w   = tid >> 6, l = tid & 63;
  const int l31 = l & 31, hi = l >> 5;
  const int bm = blockIdx.y * 128, bn = blockIdx.x * 128;
  const int wm = (w >> 1) * 64,    wn = (w & 1) * 64;

  f32x16 acc[2][2] = {};

  const int r0   = w * 32;
  const int srow = l >> 3;
  const int gch  = (l & 7) ^ (srow & 7);
  const f16* Ag = A + (long)(bm + r0 + srow) * K + gch * 8;
  const f16* Bg = B + (long)(bn + r0 + srow) * K + gch * 8;
  f16* lA = &As[r0 * 64];
  f16* lB = &Bs[r0 * 64];
  const long rs8 = 8L * K;
  const int swz = l & 7;

  for (int k0 = 0; k0 < K; k0 += 64) {
#pragma unroll
    for (int g = 0; g < 4; g++) {
      glds16(Ag + g * rs8 + k0, lA + g * 512);
      glds16(Bg + g * rs8 + k0, lB + g * 512);
    }
    __syncthreads();

#pragma unroll
    for (int ks = 0; ks < 4; ks++) {
      const int pos = ((ks * 2 + hi) ^ swz) * 8;
      f16x8 af[2], bf[2];
#pragma unroll
      for (int mi = 0; mi < 2; mi++)
        af[mi] = *(const f16x8*)&As[(wm + mi * 32 + l31) * 64 + pos];
#pragma unroll
      for (int nj = 0; nj < 2; nj++)
        bf[nj] = *(const f16x8*)&Bs[(wn + nj * 32 + l31) * 64 + pos];
#pragma unroll
      for (int mi = 0; mi < 2; mi++)
#pragma unroll
        for (int nj = 0; nj < 2; nj++)
          acc[mi][nj] = __builtin_amdgcn_mfma_f32_32x32x16_f16(af[mi], bf[nj], acc[mi][nj], 0, 0, 0);
    }
    __syncthreads();
  }

#pragma unroll
  for (int mi = 0; mi < 2; mi++)
#pragma unroll
    for (int nj = 0; nj < 2; nj++) {
      const int col = bn + wn + nj * 32 + l31;
      const float bvv = bias[col];
      const int rowb = bm + wm + mi * 32 + 4 * hi;
#pragma unroll
      for (int reg = 0; reg < 16; reg++) {
        const int row = rowb + (reg & 3) + 8 * (reg >> 2);
        Cv[(long)row * N + col] = acc[mi][nj][reg] + bvv;
      }
    }
}

// ---------------------------------------------------------------------------
// Fused Q prep: one pass over q -> qrot (RoPE) and qnorm (RMSNorm*D^-0.5).
__global__ void k_qprep(const f16* __restrict__ x, const float* __restrict__ snp,
                        const float* __restrict__ csp, const float* __restrict__ scale,
                        f16* __restrict__ qrot, f16* __restrict__ qnorm, int rows) {
  int gw = (blockIdx.x * 256 + threadIdx.x) >> 6;
  int l  = threadIdx.x & 63;
  if (gw >= rows) return;
  long base = (long)gw * HD;
  int s = gw / NH;
  int d = 2 * l;
  float a = (float)x[base + d];
  float b = (float)x[base + d + 1];

  float ss = a * a + b * b;
#pragma unroll
  for (int off = 32; off >= 1; off >>= 1) ss += __shfl_xor(ss, off, 64);
  float rms = sqrtf(ss * (1.0f / HD));
  float inv = 0.08838834764831845f / (rms + 1e-6f);
  qnorm[base + d]     = (f16)(a * scale[d] * inv);
  qnorm[base + d + 1] = (f16)(b * scale[d + 1] * inv);

  float pa = __shfl_xor(a, 16, 64);
  float pb = __shfl_xor(b, 16, 64);
  float ra, rb;
  if (d < 64) {
    float sgn = (d < 32) ? -1.0f : 1.0f;
    ra = a * csp[s * 64 + d]     + sgn * pa * snp[s * 64 + d];
    rb = b * csp[s * 64 + d + 1] + sgn * pb * snp[s * 64 + d + 1];
  } else {
    ra = a; rb = b;
  }
  qrot[base + d]     = (f16)ra;
  qrot[base + d + 1] = (f16)rb;
}

// ---------------------------------------------------------------------------
// K-self: RoPE + pack into QK B-fragment order (one pass).
__global__ void k_krope_pack(const f16* __restrict__ src, const float* __restrict__ snp,
                             const float* __restrict__ csp, f16* __restrict__ dst,
                             int T, int nchunk) {
  int i = blockIdx.x * 256 + threadIdx.x;
  if (i >= nchunk) return;
  int d8 = i % 384;
  int t  = i / 384;
  int h  = d8 >> 4;
  int d  = (d8 & 15) * 8;
  f16x8 x = *(const f16x8*)(src + (long)i * 8);
  f16x8 o;
  if (d < 64) {
    f16x8 p = (d < 32) ? *(const f16x8*)(src + (long)i * 8 + 32)
                       : *(const f16x8*)(src + (long)i * 8 - 32);
    float sgn = (d < 32) ? -1.0f : 1.0f;
#pragma unroll
    for (int j = 0; j < 8; j++) {
      float cs = csp[t * 64 + d + j], sn = snp[t * 64 + d + j];
      o[j] = (f16)((float)x[j] * cs + sgn * (float)p[j] * sn);
    }
  } else {
    o = x;
  }
  long off = ((((long)h * (T >> 4) + (t >> 4)) * 4 + (d >> 5)) * 64 + ((d >> 3) & 3) * 16 + (t & 15)) * 8;
  *(f16x8*)(dst + off) = o;
}

// ---------------------------------------------------------------------------
// K-ip: RMSNorm*D^-0.5 + pack into QK B-fragment order (one pass).
__global__ void k_rms_pack(const f16* __restrict__ x, const float* __restrict__ scale,
                           f16* __restrict__ dst, int T, int rows) {
  int gw  = (blockIdx.x * 256 + threadIdx.x) >> 6;
  int l   = threadIdx.x & 63;
  int sub = l >> 4, l16 = l & 15;
  int row = gw * 4 + sub;
  if (row >= rows) return;
  int t = row / NH, h = row - t * NH;
  int d = l16 * 8;
  f16x8 v = *(const f16x8*)(x + (long)row * HD + d);
  float ss = 0.f;
#pragma unroll
  for (int j = 0; j < 8; j++) { float f = (float)v[j]; ss += f * f; }
  ss += __shfl_xor(ss, 1, 64);
  ss += __shfl_xor(ss, 2, 64);
  ss += __shfl_xor(ss, 4, 64);
  ss += __shfl_xor(ss, 8, 64);
  float rms = sqrtf(ss * (1.0f / HD));
  float inv = 0.08838834764831845f / (rms + 1e-6f);
  f16x8 o;
#pragma unroll
  for (int j = 0; j < 8; j++) o[j] = (f16)((float)v[j] * scale[d + j] * inv);
  long off = ((((long)h * (T >> 4) + (t >> 4)) * 4 + (d >> 5)) * 64 + ((d >> 3) & 3) * 16 + (t & 15)) * 8;
  *(f16x8*)(dst + off) = o;
}

// ---------------------------------------------------------------------------
// Pack V [T][HID] -> PV B-fragment order (transposed: frag j indexes t).
__global__ __launch_bounds__(256) void k_vpack(const f16* __restrict__ v, f16* __restrict__ dst, int T) {
  __shared__ f16 Ts[128 * 72];   // [d][t], ld=72
  int h = blockIdx.y, tb = blockIdx.x, t0 = tb * 64;
  int tid = threadIdx.x;
  int r = tid >> 2, c4 = tid & 3;
#pragma unroll
  for (int cc = 0; cc < 4; cc++) {
    int ch = c4 * 4 + cc;
    f16x8 x = *(const f16x8*)(v + (long)(t0 + r) * HID + h * HD + ch * 8);
#pragma unroll
    for (int j = 0; j < 8; j++)
      Ts[(ch * 8 + j) * 72 + r] = x[j];
  }
  __syncthreads();
  int l16 = tid & 15, jd = (tid >> 4) & 7, ks = tid >> 7;
#pragma unroll
  for (int quad = 0; quad < 4; quad++) {
    f16x8 x = *(const f16x8*)&Ts[(jd * 16 + l16) * 72 + ks * 32 + quad * 8];
    long off = ((((long)h * (T >> 6) + tb) * 2 + ks) * 8 + jd) * 512 + (quad * 16 + l16) * 8;
    *(f16x8*)(dst + off) = x;
  }
}

// ---------------------------------------------------------------------------
// Flash attention with split-T, XCD-grouped 1-D grid (16*NH*nsp blocks).
// The 16 q-blocks sharing one (head, split) K/V slice (256 KB) are mapped to
// ids congruent mod 8 -> same XCD -> K/V L2-resident; cuts the ~3x HBM
// over-fetch and the critical-path load latency (HBM ~900cyc -> L2 ~200cyc).
// Bijection: L = (xcd) + 8*(j + 16*ghi); g = ghi*8+xcd; (h,sp) = (g%NH, g/NH).
__global__ __launch_bounds__(256, 3) void k_flash2(
    const f16* __restrict__ Q, const f16* __restrict__ Kp, const f16* __restrict__ Vp,
    f16* __restrict__ Opart, long part_stride, float2* __restrict__ ml, int p0,
    int T, int Tc)
{
  __shared__ f16 Ps[4][32 * 72];   // per-wave P tile, no barrier needed

  // --- XCD-grouping remap ---
  const int L    = blockIdx.x;
  const int xcd  = L & 7;
  const int slot = L >> 3;
  const int j    = slot & 15;          // q-tile
  const int g    = (slot >> 4) * 8 + xcd;
  const int h    = g % NH;
  const int sp   = g / NH;

  const int tid  = threadIdx.x, w = tid >> 6, l = tid & 63;
  const int quad = l >> 4, l16 = l & 15;
  const int qr   = j * 128 + w * 32;
  const int Tt16 = T >> 4, Tt64 = T >> 6;

  f16x8 qf[2][4];
#pragma unroll
  for (int mt = 0; mt < 2; mt++)
#pragma unroll
    for (int kq = 0; kq < 4; kq++)
      qf[mt][kq] = *(const f16x8*)(Q + (long)(qr + mt * 16 + l16) * HID + h * HD + kq * 32 + quad * 8);

  f32x4 o[2][8] = {};
  float m_run[8], l_run[8];
#pragma unroll
  for (int i = 0; i < 8; i++) { m_run[i] = -1e30f; l_run[i] = 0.f; }

  f16* myP = &Ps[w][0];
  const int t_begin = sp * Tc, t_end = t_begin + Tc;

  for (int t0 = t_begin; t0 < t_end; t0 += 64) {
    f32x4 s[2][4] = {};
#pragma unroll
    for (int kq = 0; kq < 4; kq++) {
      f16x8 kf[4];
#pragma unroll
      for (int jn = 0; jn < 4; jn++)
        kf[jn] = *(const f16x8*)(Kp + (((long)(h * Tt16 + (t0 >> 4) + jn) * 4 + kq) * 64 + l) * 8);
#pragma unroll
      for (int mt = 0; mt < 2; mt++)
#pragma unroll
        for (int jn = 0; jn < 4; jn++)
          s[mt][jn] = __builtin_amdgcn_mfma_f32_16x16x32_f16(qf[mt][kq], kf[jn], s[mt][jn], 0, 0, 0);
    }

#pragma unroll
    for (int mt = 0; mt < 2; mt++) {
#pragma unroll
      for (int r = 0; r < 4; r++) {
        float mx = fmaxf(fmaxf(s[mt][0][r], s[mt][1][r]), fmaxf(s[mt][2][r], s[mt][3][r]));
        mx = fmaxf(mx, __shfl_xor(mx, 1, 64));
        mx = fmaxf(mx, __shfl_xor(mx, 2, 64));
        mx = fmaxf(mx, __shfl_xor(mx, 4, 64));
        mx = fmaxf(mx, __shfl_xor(mx, 8, 64));
        const int ri = mt * 4 + r;
        float mn = fmaxf(m_run[ri], mx);
        float al = __expf(m_run[ri] - mn);
        m_run[ri] = mn;
        float p0v = __expf(s[mt][0][r] - mn);
        float p1v = __expf(s[mt][1][r] - mn);
        float p2v = __expf(s[mt][2][r] - mn);
        float p3v = __expf(s[mt][3][r] - mn);
        s[mt][0][r] = p0v; s[mt][1][r] = p1v; s[mt][2][r] = p2v; s[mt][3][r] = p3v;
        l_run[ri] = l_run[ri] * al + (p0v + p1v + p2v + p3v);
#pragma unroll
        for (int jd = 0; jd < 8; jd++) o[mt][jd][r] *= al;
      }
    }

#pragma unroll
    for (int mt = 0; mt < 2; mt++)
#pragma unroll
      for (int jn = 0; jn < 4; jn++)
#pragma unroll
        for (int r = 0; r < 4; r++)
          myP[(mt * 16 + quad * 4 + r) * 72 + jn * 16 + l16] = (f16)s[mt][jn][r];

#pragma unroll
    for (int ks = 0; ks < 2; ks++) {
      f16x8 pf[2];
#pragma unroll
      for (int mt = 0; mt < 2; mt++)
        pf[mt] = *(const f16x8*)&myP[(mt * 16 + l16) * 72 + ks * 32 + quad * 8];
      f16x8 vf[8];
#pragma unroll
      for (int jd = 0; jd < 8; jd++)
        vf[jd] = *(const f16x8*)(Vp + ((((long)(h * Tt64 + (t0 >> 6)) * 2 + ks) * 8 + jd) * 64 + l) * 8);
#pragma unroll
      for (int jd = 0; jd < 8; jd++)
#pragma unroll
        for (int mt = 0; mt < 2; mt++)
          o[mt][jd] = __builtin_amdgcn_mfma_f32_16x16x32_f16(pf[mt], vf[jd], o[mt][jd], 0, 0, 0);
    }
  }

#pragma unroll
  for (int i = 0; i < 8; i++) {
    float v = l_run[i];
    v += __shfl_xor(v, 1, 64);
    v += __shfl_xor(v, 2, 64);
    v += __shfl_xor(v, 4, 64);
    v += __shfl_xor(v, 8, 64);
    l_run[i] = v;
  }

  f16* Od = Opart + (long)sp * part_stride;
#pragma unroll
  for (int mt = 0; mt < 2; mt++)
#pragma unroll
    for (int jd = 0; jd < 8; jd++)
#pragma unroll
      for (int r = 0; r < 4; r++) {
        int row = qr + mt * 16 + quad * 4 + r;
        int col = h * HD + jd * 16 + l16;
        Od[(long)row * HID + col] = (f16)o[mt][jd][r];
      }
  if (l16 == 0) {
#pragma unroll
    for (int mt = 0; mt < 2; mt++)
#pragma unroll
      for (int r = 0; r < 4; r++) {
        int row = qr + mt * 16 + quad * 4 + r;
        float2 v; v.x = m_run[mt * 4 + r]; v.y = l_run[mt * 4 + r];
        ml[((long)(p0 + sp) * NH + h) * S_LEN + row] = v;
      }
  }
}

// ---------------------------------------------------------------------------
// Combine: out = sum_p w_p O_p (stream1: p0..3, stream2: p4..5), per f16x8 chunk
__global__ void k_combine(const f16* __restrict__ O0, const f16* __restrict__ O1,
                          const f16* __restrict__ O2, const f16* __restrict__ O3,
                          const f16* __restrict__ O4, const f16* __restrict__ O5,
                          const float2* __restrict__ ml, f16* __restrict__ out, int nchunk) {
  int i = blockIdx.x * 256 + threadIdx.x;
  if (i >= nchunk) return;
  int s = i / 384, d8 = i - s * 384, h = d8 >> 4;
  long base = (long)h * S_LEN + s;
  float2 a0 = ml[0 * NH * S_LEN + base];
  float2 a1 = ml[1L * NH * S_LEN + base];
  float2 a2 = ml[2L * NH * S_LEN + base];
  float2 a3 = ml[3L * NH * S_LEN + base];
  float2 a4 = ml[4L * NH * S_LEN + base];
  float2 a5 = ml[5L * NH * S_LEN + base];
  float M1 = fmaxf(fmaxf(a0.x, a1.x), fmaxf(a2.x, a3.x));
  float e0 = __expf(a0.x - M1), e1 = __expf(a1.x - M1), e2 = __expf(a2.x - M1), e3 = __expf(a3.x - M1);
  float L1 = a0.y * e0 + a1.y * e1 + a2.y * e2 + a3.y * e3;
  float w0 = e0 / L1, w1 = e1 / L1, w2 = e2 / L1, w3 = e3 / L1;
  float M2 = fmaxf(a4.x, a5.x);
  float e4 = __expf(a4.x - M2), e5 = __expf(a5.x - M2);
  float L2 = a4.y * e4 + a5.y * e5;
  float w4 = e4 / L2, w5 = e5 / L2;
  f16x8 v0 = ((const f16x8*)O0)[i];
  f16x8 v1 = ((const f16x8*)O1)[i];
  f16x8 v2 = ((const f16x8*)O2)[i];
  f16x8 v3 = ((const f16x8*)O3)[i];
  f16x8 v4 = ((const f16x8*)O4)[i];
  f16x8 v5 = ((const f16x8*)O5)[i];
  f16x8 r;
#pragma unroll
  for (int j = 0; j < 8; j++) {
    float acc = w0 * (float)v0[j] + w1 * (float)v1[j] + w2 * (float)v2[j] + w3 * (float)v3[j]
              + w4 * (float)v4[j] + w5 * (float)v5[j];
    r[j] = (f16)acc;
  }
  ((f16x8*)out)[i] = r;
}

// ---------------------------------------------------------------------------
extern "C" void kernel_launch(void* const* d_in, const int* in_sizes, int n_in,
                              void* d_out, int out_size, void* d_ws, size_t ws_size,
                              hipStream_t stream) {
  const float* hs   = (const float*)d_in[0];
  const float* ip   = (const float*)d_in[1];
  const float* snp  = (const float*)d_in[2];
  const float* csp  = (const float*)d_in[3];
  const float* Wq   = (const float*)d_in[4];
  const float* bq   = (const float*)d_in[5];
  const float* Wk   = (const float*)d_in[6];
  const float* bk   = (const float*)d_in[7];
  const float* Wv   = (const float*)d_in[8];
  const float* bv   = (const float*)d_in[9];
  const float* Wo   = (const float*)d_in[10];
  const float* bo   = (const float*)d_in[11];
  const float* Wkip = (const float*)d_in[12];
  const float* bkip = (const float*)d_in[13];
  const float* Wvip = (const float*)d_in[14];
  const float* bvip = (const float*)d_in[15];
  const float* qs   = (const float*)d_in[16];
  const float* ks   = (const float*)d_in[17];
  float* out = (float*)d_out;

  // sizes (f16 elements)
  const long n1   = 6291456;   // 2048*3072
  const long nW   = 9437184;   // 3072*3072
  const long nip  = 589824;    // 512*1152
  const long nWip = 3538944;   // 3072*1152

  // static layout with lifetime-checked reuse
  const long o_hs   = 0;
  const long o_Wq   = 6291456;
  const long o_Wk   = 15728640;
  const long o_Wv   = 25165824;
  const long o_Wo   = 34603008;
  const long o_ip   = 44040192;
  const long o_Wkip = 44630016;
  const long o_Wvip = 48168960;
  const long o_q    = 51707904;
  const long o_k    = 57999360;
  const long o_v    = 64290816;
  const long o_kip  = 70582272;
  const long o_vip  = 72155136;
  const long o_qrot = 73728000;
  const long o_qnorm= 80019456;
  const long o_Vpip = 87883776;
  const long o_ml   = 89456640;   // float2[6*24*2048]
  const long o_Kps  = o_hs;
  const long o_Op0  = o_Wq;       // p0..p3 stride n1
  const long o_Op4  = o_Wkip;
  const long o_Op5  = o_q;
  const long o_Vps  = o_k;
  const long o_Kpip = o_kip;
  const long o_attn = o_v;

  f16* WS = (f16*)d_ws;
  auto P = [&](long off) { return WS + off; };
  float2* mlp = (float2*)(WS + o_ml);

  // 1) all casts in one launch
  CastArgs ca;
  ca.src[0] = hs;   ca.dst[0] = P(o_hs);   ca.n4[0] = n1 / 4;
  ca.src[1] = ip;   ca.dst[1] = P(o_ip);   ca.n4[1] = nip / 4;
  ca.src[2] = Wq;   ca.dst[2] = P(o_Wq);   ca.n4[2] = nW / 4;
  ca.src[3] = Wk;   ca.dst[3] = P(o_Wk);   ca.n4[3] = nW / 4;
  ca.src[4] = Wv;   ca.dst[4] = P(o_Wv);   ca.n4[4] = nW / 4;
  ca.src[5] = Wo;   ca.dst[5] = P(o_Wo);   ca.n4[5] = nW / 4;
  ca.src[6] = Wkip; ca.dst[6] = P(o_Wkip); ca.n4[6] = nWip / 4;
  ca.src[7] = Wvip; ca.dst[7] = P(o_Wvip); ca.n4[7] = nWip / 4;
  const long total4 = (n1 + nip + 4 * nW + 2 * nWip) / 4;
  k_cvt_all<<<dim3((total4 + 255) / 256), 256, 0, stream>>>(ca, total4);

  // 2) merged projections (QKV + ip, XCD-grouped 1-D grid: 1344 blocks)
  ProjArgs pa;
  pa.A0 = P(o_hs); pa.A1 = P(o_ip);
  pa.Wq = P(o_Wq); pa.Wk = P(o_Wk); pa.Wv = P(o_Wv);
  pa.Wkip = P(o_Wkip); pa.Wvip = P(o_Wvip);
  pa.bq = bq; pa.bk = bk; pa.bv = bv; pa.bkip = bkip; pa.bvip = bvip;
  pa.q = P(o_q); pa.k = P(o_k); pa.v = P(o_v);
  pa.kip = P(o_kip); pa.vip = P(o_vip);
  k_gemm_proj<<<dim3(1344), 256, 0, stream>>>(pa);

  // 3) prep (fused): qprep, krope_pack, rms_pack(ip), vpacks
  k_qprep<<<dim3(49152 / 4), 256, 0, stream>>>(P(o_q), snp, csp, qs, P(o_qrot), P(o_qnorm), 49152);
  k_krope_pack<<<dim3(786432 / 256), 256, 0, stream>>>(P(o_k), snp, csp, P(o_Kps), 2048, 786432);
  k_rms_pack<<<dim3(12288 / 16), 256, 0, stream>>>(P(o_kip), ks, P(o_Kpip), 512, 12288);
  k_vpack<<<dim3(32, 24), 256, 0, stream>>>(P(o_v),   P(o_Vps),  2048);
  k_vpack<<<dim3(8, 24),  256, 0, stream>>>(P(o_vip), P(o_Vpip), 512);

  // 4) flash with split-T, XCD-grouped 1-D grids
  //    (self: 4 splits of 512 -> 1536 blocks; ip: 2 splits of 256 -> 768)
  k_flash2<<<dim3(1536), 256, 0, stream>>>(P(o_qrot), P(o_Kps), P(o_Vps),
      P(o_Op0), n1, mlp, 0, 2048, 512);
  k_flash2<<<dim3(768), 256, 0, stream>>>(P(o_qnorm), P(o_Kpip), P(o_Vpip),
      P(o_Op4), o_Op5 - o_Op4, mlp, 4, 512, 256);

  // 5) combine partials -> attn (f16)
  k_combine<<<dim3(786432 / 256), 256, 0, stream>>>(
      P(o_Op0), P(o_Op0 + n1), P(o_Op0 + 2 * n1), P(o_Op0 + 3 * n1),
      P(o_Op4), P(o_Op5), mlp, P(o_attn), 786432);

  // 6) output projection -> fp32 d_out
  k_gemm_nt<<<dim3(24, 16, 1), 256, 0, stream>>>(P(o_attn),
      P(o_Wo), bo, out, 2048, 3072, 3072);
}

// Round 6
// 636.295 us; speedup vs baseline: 1.0642x; 1.0642x over previous
//
#include <hip/hip_runtime.h>
#include <stdint.h>

// Problem constants
#define S_LEN 2048
#define NH    24
#define HD    128
#define HID   3072    // NH*HD
#define IPS   512
#define IPD   1152

using f16   = __fp16;
using f16x4 = __fp16 __attribute__((ext_vector_type(4)));
using f16x8 = __fp16 __attribute__((ext_vector_type(8)));
using f32x4 = float  __attribute__((ext_vector_type(4)));
using f32x16 = float __attribute__((ext_vector_type(16)));

// ---------------------------------------------------------------------------
// async global->LDS, 16B per lane. LDS dest is wave-uniform base + lane*16.
__device__ __forceinline__ void glds16(const f16* g, f16* l) {
  __builtin_amdgcn_global_load_lds((const __attribute__((address_space(1))) void*)g,
                                   (__attribute__((address_space(3))) void*)l,
                                   16, 0, 0);
}

// ---------------------------------------------------------------------------
// DPP 16-lane-group reductions (VALU-only; avoids ds_bpermute lgkm stalls).
// quad_perm[1,0,3,2]=0xB1 (xor1), quad_perm[2,3,0,1]=0x4E (xor2),
// row_half_mirror=0x141 (pairs 4-groups within 8), row_mirror=0x140 (pairs 8s).
__device__ __forceinline__ float red16_max(float x) {
  x = fmaxf(x, __int_as_float(__builtin_amdgcn_mov_dpp(__float_as_int(x), 0xB1, 0xf, 0xf, true)));
  x = fmaxf(x, __int_as_float(__builtin_amdgcn_mov_dpp(__float_as_int(x), 0x4E, 0xf, 0xf, true)));
  x = fmaxf(x, __int_as_float(__builtin_amdgcn_mov_dpp(__float_as_int(x), 0x141, 0xf, 0xf, true)));
  x = fmaxf(x, __int_as_float(__builtin_amdgcn_mov_dpp(__float_as_int(x), 0x140, 0xf, 0xf, true)));
  return x;
}
__device__ __forceinline__ float red16_sum(float x) {
  x += __int_as_float(__builtin_amdgcn_mov_dpp(__float_as_int(x), 0xB1, 0xf, 0xf, true));
  x += __int_as_float(__builtin_amdgcn_mov_dpp(__float_as_int(x), 0x4E, 0xf, 0xf, true));
  x += __int_as_float(__builtin_amdgcn_mov_dpp(__float_as_int(x), 0x141, 0xf, 0xf, true));
  x += __int_as_float(__builtin_amdgcn_mov_dpp(__float_as_int(x), 0x140, 0xf, 0xf, true));
  return x;
}

// ---------------------------------------------------------------------------
// cast kernel: only hs and ip now (weights are consumed fp32 by the GEMMs)
__global__ void k_cvt2(const float* __restrict__ a, f16* __restrict__ da, long n4a,
                       const float* __restrict__ b, f16* __restrict__ db, long total4) {
  long i = blockIdx.x * 256L + threadIdx.x;
  if (i >= total4) return;
  const float* s; f16* d; long r;
  if (i < n4a) { s = a; d = da; r = i; }
  else         { s = b; d = db; r = i - n4a; }
  float4 v = ((const float4*)s)[r];
  f16x4 o;
  o.x = (f16)v.x; o.y = (f16)v.y; o.z = (f16)v.z; o.w = (f16)v.w;
  ((f16x4*)d)[r] = o;
}

// ---------------------------------------------------------------------------
// Merged projection GEMM, 5 z-slices. A staged f16 via global_load_lds;
// B (weights) read fp32 DIRECTLY from kernel inputs and converted during
// reg-staging (float4 x2 -> 8x(f16) cvt -> ds_write_b128 to the same address
// glds16 would write: lane*16B, pre-swizzled source). Same LDS layout/swizzle,
// same RTN rounding as the old cast pass. GEMM tolerates the extra HBM fetch
// (proven r5: 2x fetch cost ~2us) and the cast pass shrinks by ~85%.
struct ProjArgs {
  const f16 *A0, *A1;                               // hs, ip (f16 from cast)
  const float *Wq, *Wk, *Wv, *Wkip, *Wvip;          // fp32 weights (direct)
  const float *bq, *bk, *bv, *bkip, *bvip;
  f16 *q, *k, *v, *kip, *vip;
};

__global__ __launch_bounds__(256) void k_gemm_proj(ProjArgs pa) {
  const int z = blockIdx.z;
  const f16* A; const float* B; const float* bias; f16* C; int K;
  if (z == 0)      { A = pa.A0; B = pa.Wq;   bias = pa.bq;   C = pa.q;   K = 3072; }
  else if (z == 1) { A = pa.A0; B = pa.Wk;   bias = pa.bk;   C = pa.k;   K = 3072; }
  else if (z == 2) { A = pa.A0; B = pa.Wv;   bias = pa.bv;   C = pa.v;   K = 3072; }
  else if (z == 3) { if (blockIdx.y >= 4) return;
                     A = pa.A1; B = pa.Wkip; bias = pa.bkip; C = pa.kip; K = 1152; }
  else             { if (blockIdx.y >= 4) return;
                     A = pa.A1; B = pa.Wvip; bias = pa.bvip; C = pa.vip; K = 1152; }

  __shared__ f16 As[128 * 64];
  __shared__ f16 Bs[128 * 64];

  const int tid = threadIdx.x;
  const int w   = tid >> 6, l = tid & 63;
  const int l31 = l & 31, hi = l >> 5;
  const int bm = blockIdx.y * 128, bn = blockIdx.x * 128;
  const int wm = (w >> 1) * 64,    wn = (w & 1) * 64;

  f32x16 acc[2][2] = {};

  const int r0   = w * 32;
  const int srow = l >> 3;
  const int gch  = (l & 7) ^ (srow & 7);
  const f16*   Ag = A + (long)(bm + r0 + srow) * K + gch * 8;
  const float* Bg = B + (long)(bn + r0 + srow) * K + gch * 8;
  f16* lA = &As[r0 * 64];
  f16* lB = &Bs[r0 * 64];
  const long rs8 = 8L * K;
  const int swz = l & 7;

  for (int k0 = 0; k0 < K; k0 += 64) {
#pragma unroll
    for (int g = 0; g < 4; g++)
      glds16(Ag + g * rs8 + k0, lA + g * 512);
#pragma unroll
    for (int g = 0; g < 4; g++) {
      const float* src = Bg + g * rs8 + k0;
      float4 u0 = *(const float4*)src;
      float4 u1 = *(const float4*)(src + 4);
      f16x8 hh;
      hh[0] = (f16)u0.x; hh[1] = (f16)u0.y; hh[2] = (f16)u0.z; hh[3] = (f16)u0.w;
      hh[4] = (f16)u1.x; hh[5] = (f16)u1.y; hh[6] = (f16)u1.z; hh[7] = (f16)u1.w;
      *(f16x8*)(lB + g * 512 + l * 8) = hh;
    }
    __syncthreads();

#pragma unroll
    for (int ks = 0; ks < 4; ks++) {
      const int pos = ((ks * 2 + hi) ^ swz) * 8;
      f16x8 af[2], bf[2];
#pragma unroll
      for (int mi = 0; mi < 2; mi++)
        af[mi] = *(const f16x8*)&As[(wm + mi * 32 + l31) * 64 + pos];
#pragma unroll
      for (int nj = 0; nj < 2; nj++)
        bf[nj] = *(const f16x8*)&Bs[(wn + nj * 32 + l31) * 64 + pos];
#pragma unroll
      for (int mi = 0; mi < 2; mi++)
#pragma unroll
        for (int nj = 0; nj < 2; nj++)
          acc[mi][nj] = __builtin_amdgcn_mfma_f32_32x32x16_f16(af[mi], bf[nj], acc[mi][nj], 0, 0, 0);
    }
    __syncthreads();
  }

  // epilogue: C/D layout col=lane&31, row=(reg&3)+8*(reg>>2)+4*(lane>>5)
#pragma unroll
  for (int mi = 0; mi < 2; mi++)
#pragma unroll
    for (int nj = 0; nj < 2; nj++) {
      const int col = bn + wn + nj * 32 + l31;
      const float bvv = bias[col];
      const int rowb = bm + wm + mi * 32 + 4 * hi;
#pragma unroll
      for (int reg = 0; reg < 16; reg++) {
        const int row = rowb + (reg & 3) + 8 * (reg >> 2);
        C[(long)row * HID + col] = (f16)(acc[mi][nj][reg] + bvv);
      }
    }
}

// ---------------------------------------------------------------------------
// NT GEMM (out-projection): A f16 via glds16, B = Wo fp32 reg-staged, fp32 out.
__global__ __launch_bounds__(256) void k_gemm_nt(
    const f16* __restrict__ A, const float* __restrict__ B,
    const float* __restrict__ bias, float* __restrict__ Cv,
    int M, int N, int K)
{
  __shared__ f16 As[128 * 64];
  __shared__ f16 Bs[128 * 64];

  const int tid = threadIdx.x;
  const int w   = tid >> 6, l = tid & 63;
  const int l31 = l & 31, hi = l >> 5;
  const int bm = blockIdx.y * 128, bn = blockIdx.x * 128;
  const int wm = (w >> 1) * 64,    wn = (w & 1) * 64;

  f32x16 acc[2][2] = {};

  const int r0   = w * 32;
  const int srow = l >> 3;
  const int gch  = (l & 7) ^ (srow & 7);
  const f16*   Ag = A + (long)(bm + r0 + srow) * K + gch * 8;
  const float* Bg = B + (long)(bn + r0 + srow) * K + gch * 8;
  f16* lA = &As[r0 * 64];
  f16* lB = &Bs[r0 * 64];
  const long rs8 = 8L * K;
  const int swz = l & 7;

  for (int k0 = 0; k0 < K; k0 += 64) {
#pragma unroll
    for (int g = 0; g < 4; g++)
      glds16(Ag + g * rs8 + k0, lA + g * 512);
#pragma unroll
    for (int g = 0; g < 4; g++) {
      const float* src = Bg + g * rs8 + k0;
      float4 u0 = *(const float4*)src;
      float4 u1 = *(const float4*)(src + 4);
      f16x8 hh;
      hh[0] = (f16)u0.x; hh[1] = (f16)u0.y; hh[2] = (f16)u0.z; hh[3] = (f16)u0.w;
      hh[4] = (f16)u1.x; hh[5] = (f16)u1.y; hh[6] = (f16)u1.z; hh[7] = (f16)u1.w;
      *(f16x8*)(lB + g * 512 + l * 8) = hh;
    }
    __syncthreads();

#pragma unroll
    for (int ks = 0; ks < 4; ks++) {
      const int pos = ((ks * 2 + hi) ^ swz) * 8;
      f16x8 af[2], bf[2];
#pragma unroll
      for (int mi = 0; mi < 2; mi++)
        af[mi] = *(const f16x8*)&As[(wm + mi * 32 + l31) * 64 + pos];
#pragma unroll
      for (int nj = 0; nj < 2; nj++)
        bf[nj] = *(const f16x8*)&Bs[(wn + nj * 32 + l31) * 64 + pos];
#pragma unroll
      for (int mi = 0; mi < 2; mi++)
#pragma unroll
        for (int nj = 0; nj < 2; nj++)
          acc[mi][nj] = __builtin_amdgcn_mfma_f32_32x32x16_f16(af[mi], bf[nj], acc[mi][nj], 0, 0, 0);
    }
    __syncthreads();
  }

#pragma unroll
  for (int mi = 0; mi < 2; mi++)
#pragma unroll
    for (int nj = 0; nj < 2; nj++) {
      const int col = bn + wn + nj * 32 + l31;
      const float bvv = bias[col];
      const int rowb = bm + wm + mi * 32 + 4 * hi;
#pragma unroll
      for (int reg = 0; reg < 16; reg++) {
        const int row = rowb + (reg & 3) + 8 * (reg >> 2);
        Cv[(long)row * N + col] = acc[mi][nj][reg] + bvv;
      }
    }
}

// ---------------------------------------------------------------------------
// Fused Q prep: one pass over q -> qrot (RoPE) and qnorm (RMSNorm*D^-0.5).
__global__ void k_qprep(const f16* __restrict__ x, const float* __restrict__ snp,
                        const float* __restrict__ csp, const float* __restrict__ scale,
                        f16* __restrict__ qrot, f16* __restrict__ qnorm, int rows) {
  int gw = (blockIdx.x * 256 + threadIdx.x) >> 6;
  int l  = threadIdx.x & 63;
  if (gw >= rows) return;
  long base = (long)gw * HD;
  int s = gw / NH;
  int d = 2 * l;
  float a = (float)x[base + d];
  float b = (float)x[base + d + 1];

  float ss = a * a + b * b;
#pragma unroll
  for (int off = 32; off >= 1; off >>= 1) ss += __shfl_xor(ss, off, 64);
  float rms = sqrtf(ss * (1.0f / HD));
  float inv = 0.08838834764831845f / (rms + 1e-6f);
  qnorm[base + d]     = (f16)(a * scale[d] * inv);
  qnorm[base + d + 1] = (f16)(b * scale[d + 1] * inv);

  float pa = __shfl_xor(a, 16, 64);
  float pb = __shfl_xor(b, 16, 64);
  float ra, rb;
  if (d < 64) {
    float sgn = (d < 32) ? -1.0f : 1.0f;
    ra = a * csp[s * 64 + d]     + sgn * pa * snp[s * 64 + d];
    rb = b * csp[s * 64 + d + 1] + sgn * pb * snp[s * 64 + d + 1];
  } else {
    ra = a; rb = b;
  }
  qrot[base + d]     = (f16)ra;
  qrot[base + d + 1] = (f16)rb;
}

// ---------------------------------------------------------------------------
// K-self: RoPE + pack into QK B-fragment order (one pass).
__global__ void k_krope_pack(const f16* __restrict__ src, const float* __restrict__ snp,
                             const float* __restrict__ csp, f16* __restrict__ dst,
                             int T, int nchunk) {
  int i = blockIdx.x * 256 + threadIdx.x;
  if (i >= nchunk) return;
  int d8 = i % 384;
  int t  = i / 384;
  int h  = d8 >> 4;
  int d  = (d8 & 15) * 8;
  f16x8 x = *(const f16x8*)(src + (long)i * 8);
  f16x8 o;
  if (d < 64) {
    f16x8 p = (d < 32) ? *(const f16x8*)(src + (long)i * 8 + 32)
                       : *(const f16x8*)(src + (long)i * 8 - 32);
    float sgn = (d < 32) ? -1.0f : 1.0f;
#pragma unroll
    for (int j = 0; j < 8; j++) {
      float cs = csp[t * 64 + d + j], sn = snp[t * 64 + d + j];
      o[j] = (f16)((float)x[j] * cs + sgn * (float)p[j] * sn);
    }
  } else {
    o = x;
  }
  long off = ((((long)h * (T >> 4) + (t >> 4)) * 4 + (d >> 5)) * 64 + ((d >> 3) & 3) * 16 + (t & 15)) * 8;
  *(f16x8*)(dst + off) = o;
}

// ---------------------------------------------------------------------------
// K-ip: RMSNorm*D^-0.5 + pack into QK B-fragment order (one pass).
__global__ void k_rms_pack(const f16* __restrict__ x, const float* __restrict__ scale,
                           f16* __restrict__ dst, int T, int rows) {
  int gw  = (blockIdx.x * 256 + threadIdx.x) >> 6;
  int l   = threadIdx.x & 63;
  int sub = l >> 4, l16 = l & 15;
  int row = gw * 4 + sub;
  if (row >= rows) return;
  int t = row / NH, h = row - t * NH;
  int d = l16 * 8;
  f16x8 v = *(const f16x8*)(x + (long)row * HD + d);
  float ss = 0.f;
#pragma unroll
  for (int j = 0; j < 8; j++) { float f = (float)v[j]; ss += f * f; }
  ss += __shfl_xor(ss, 1, 64);
  ss += __shfl_xor(ss, 2, 64);
  ss += __shfl_xor(ss, 4, 64);
  ss += __shfl_xor(ss, 8, 64);
  float rms = sqrtf(ss * (1.0f / HD));
  float inv = 0.08838834764831845f / (rms + 1e-6f);
  f16x8 o;
#pragma unroll
  for (int j = 0; j < 8; j++) o[j] = (f16)((float)v[j] * scale[d + j] * inv);
  long off = ((((long)h * (T >> 4) + (t >> 4)) * 4 + (d >> 5)) * 64 + ((d >> 3) & 3) * 16 + (t & 15)) * 8;
  *(f16x8*)(dst + off) = o;
}

// ---------------------------------------------------------------------------
// Pack V [T][HID] -> PV B-fragment order (transposed: frag j indexes t).
__global__ __launch_bounds__(256) void k_vpack(const f16* __restrict__ v, f16* __restrict__ dst, int T) {
  __shared__ f16 Ts[128 * 72];   // [d][t], ld=72
  int h = blockIdx.y, tb = blockIdx.x, t0 = tb * 64;
  int tid = threadIdx.x;
  int r = tid >> 2, c4 = tid & 3;
#pragma unroll
  for (int cc = 0; cc < 4; cc++) {
    int ch = c4 * 4 + cc;
    f16x8 x = *(const f16x8*)(v + (long)(t0 + r) * HID + h * HD + ch * 8);
#pragma unroll
    for (int j = 0; j < 8; j++)
      Ts[(ch * 8 + j) * 72 + r] = x[j];
  }
  __syncthreads();
  int l16 = tid & 15, jd = (tid >> 4) & 7, ks = tid >> 7;
#pragma unroll
  for (int quad = 0; quad < 4; quad++) {
    f16x8 x = *(const f16x8*)&Ts[(jd * 16 + l16) * 72 + ks * 32 + quad * 8];
    long off = ((((long)h * (T >> 6) + tb) * 2 + ks) * 8 + jd) * 512 + (quad * 16 + l16) * 8;
    *(f16x8*)(dst + off) = x;
  }
}

// ---------------------------------------------------------------------------
// Flash attention with split-T. Block = (128 q-rows, head, T-split).
// Softmax reductions via DPP (VALU) instead of __shfl_xor (ds_bpermute+lgkm
// stall) — the kernel is latency-bound with all pipes <25% busy, and the
// reduce chain sits on the critical path.
__global__ __launch_bounds__(256, 3) void k_flash2(
    const f16* __restrict__ Q, const f16* __restrict__ Kp, const f16* __restrict__ Vp,
    f16* __restrict__ Opart, long part_stride, float2* __restrict__ ml, int p0,
    int T, int Tc)
{
  __shared__ f16 Ps[4][32 * 72];   // per-wave P tile, no barrier needed

  const int h    = blockIdx.y;
  const int sp   = blockIdx.z;
  const int tid  = threadIdx.x, w = tid >> 6, l = tid & 63;
  const int quad = l >> 4, l16 = l & 15;
  const int qr   = blockIdx.x * 128 + w * 32;
  const int Tt16 = T >> 4, Tt64 = T >> 6;

  f16x8 qf[2][4];
#pragma unroll
  for (int mt = 0; mt < 2; mt++)
#pragma unroll
    for (int kq = 0; kq < 4; kq++)
      qf[mt][kq] = *(const f16x8*)(Q + (long)(qr + mt * 16 + l16) * HID + h * HD + kq * 32 + quad * 8);

  f32x4 o[2][8] = {};
  float m_run[8], l_run[8];
#pragma unroll
  for (int i = 0; i < 8; i++) { m_run[i] = -1e30f; l_run[i] = 0.f; }

  f16* myP = &Ps[w][0];
  const int t_begin = sp * Tc, t_end = t_begin + Tc;

  for (int t0 = t_begin; t0 < t_end; t0 += 64) {
    f32x4 s[2][4] = {};
#pragma unroll
    for (int kq = 0; kq < 4; kq++) {
      f16x8 kf[4];
#pragma unroll
      for (int jn = 0; jn < 4; jn++)
        kf[jn] = *(const f16x8*)(Kp + (((long)(h * Tt16 + (t0 >> 4) + jn) * 4 + kq) * 64 + l) * 8);
#pragma unroll
      for (int mt = 0; mt < 2; mt++)
#pragma unroll
        for (int jn = 0; jn < 4; jn++)
          s[mt][jn] = __builtin_amdgcn_mfma_f32_16x16x32_f16(qf[mt][kq], kf[jn], s[mt][jn], 0, 0, 0);
    }

#pragma unroll
    for (int mt = 0; mt < 2; mt++) {
#pragma unroll
      for (int r = 0; r < 4; r++) {
        float mx = fmaxf(fmaxf(s[mt][0][r], s[mt][1][r]), fmaxf(s[mt][2][r], s[mt][3][r]));
        mx = red16_max(mx);
        const int ri = mt * 4 + r;
        float mn = fmaxf(m_run[ri], mx);
        float al = __expf(m_run[ri] - mn);
        m_run[ri] = mn;
        float p0v = __expf(s[mt][0][r] - mn);
        float p1v = __expf(s[mt][1][r] - mn);
        float p2v = __expf(s[mt][2][r] - mn);
        float p3v = __expf(s[mt][3][r] - mn);
        s[mt][0][r] = p0v; s[mt][1][r] = p1v; s[mt][2][r] = p2v; s[mt][3][r] = p3v;
        l_run[ri] = l_run[ri] * al + (p0v + p1v + p2v + p3v);
#pragma unroll
        for (int jd = 0; jd < 8; jd++) o[mt][jd][r] *= al;
      }
    }

#pragma unroll
    for (int mt = 0; mt < 2; mt++)
#pragma unroll
      for (int jn = 0; jn < 4; jn++)
#pragma unroll
        for (int r = 0; r < 4; r++)
          myP[(mt * 16 + quad * 4 + r) * 72 + jn * 16 + l16] = (f16)s[mt][jn][r];

#pragma unroll
    for (int ks = 0; ks < 2; ks++) {
      f16x8 pf[2];
#pragma unroll
      for (int mt = 0; mt < 2; mt++)
        pf[mt] = *(const f16x8*)&myP[(mt * 16 + l16) * 72 + ks * 32 + quad * 8];
      f16x8 vf[8];
#pragma unroll
      for (int jd = 0; jd < 8; jd++)
        vf[jd] = *(const f16x8*)(Vp + ((((long)(h * Tt64 + (t0 >> 6)) * 2 + ks) * 8 + jd) * 64 + l) * 8);
#pragma unroll
      for (int jd = 0; jd < 8; jd++)
#pragma unroll
        for (int mt = 0; mt < 2; mt++)
          o[mt][jd] = __builtin_amdgcn_mfma_f32_16x16x32_f16(pf[mt], vf[jd], o[mt][jd], 0, 0, 0);
    }
  }

#pragma unroll
  for (int i = 0; i < 8; i++)
    l_run[i] = red16_sum(l_run[i]);

  f16* Od = Opart + (long)sp * part_stride;
#pragma unroll
  for (int mt = 0; mt < 2; mt++)
#pragma unroll
    for (int jd = 0; jd < 8; jd++)
#pragma unroll
      for (int r = 0; r < 4; r++) {
        int row = qr + mt * 16 + quad * 4 + r;
        int col = h * HD + jd * 16 + l16;
        Od[(long)row * HID + col] = (f16)o[mt][jd][r];
      }
  if (l16 == 0) {
#pragma unroll
    for (int mt = 0; mt < 2; mt++)
#pragma unroll
      for (int r = 0; r < 4; r++) {
        int row = qr + mt * 16 + quad * 4 + r;
        float2 v; v.x = m_run[mt * 4 + r]; v.y = l_run[mt * 4 + r];
        ml[((long)(p0 + sp) * NH + h) * S_LEN + row] = v;
      }
  }
}

// ---------------------------------------------------------------------------
// Combine: out = sum_p w_p O_p (stream1: p0..3, stream2: p4..5), per f16x8 chunk
__global__ void k_combine(const f16* __restrict__ O0, const f16* __restrict__ O1,
                          const f16* __restrict__ O2, const f16* __restrict__ O3,
                          const f16* __restrict__ O4, const f16* __restrict__ O5,
                          const float2* __restrict__ ml, f16* __restrict__ out, int nchunk) {
  int i = blockIdx.x * 256 + threadIdx.x;
  if (i >= nchunk) return;
  int s = i / 384, d8 = i - s * 384, h = d8 >> 4;
  long base = (long)h * S_LEN + s;
  float2 a0 = ml[0 * NH * S_LEN + base];
  float2 a1 = ml[1L * NH * S_LEN + base];
  float2 a2 = ml[2L * NH * S_LEN + base];
  float2 a3 = ml[3L * NH * S_LEN + base];
  float2 a4 = ml[4L * NH * S_LEN + base];
  float2 a5 = ml[5L * NH * S_LEN + base];
  float M1 = fmaxf(fmaxf(a0.x, a1.x), fmaxf(a2.x, a3.x));
  float e0 = __expf(a0.x - M1), e1 = __expf(a1.x - M1), e2 = __expf(a2.x - M1), e3 = __expf(a3.x - M1);
  float L1 = a0.y * e0 + a1.y * e1 + a2.y * e2 + a3.y * e3;
  float w0 = e0 / L1, w1 = e1 / L1, w2 = e2 / L1, w3 = e3 / L1;
  float M2 = fmaxf(a4.x, a5.x);
  float e4 = __expf(a4.x - M2), e5 = __expf(a5.x - M2);
  float L2 = a4.y * e4 + a5.y * e5;
  float w4 = e4 / L2, w5 = e5 / L2;
  f16x8 v0 = ((const f16x8*)O0)[i];
  f16x8 v1 = ((const f16x8*)O1)[i];
  f16x8 v2 = ((const f16x8*)O2)[i];
  f16x8 v3 = ((const f16x8*)O3)[i];
  f16x8 v4 = ((const f16x8*)O4)[i];
  f16x8 v5 = ((const f16x8*)O5)[i];
  f16x8 r;
#pragma unroll
  for (int j = 0; j < 8; j++) {
    float acc = w0 * (float)v0[j] + w1 * (float)v1[j] + w2 * (float)v2[j] + w3 * (float)v3[j]
              + w4 * (float)v4[j] + w5 * (float)v5[j];
    r[j] = (f16)acc;
  }
  ((f16x8*)out)[i] = r;
}

// ---------------------------------------------------------------------------
extern "C" void kernel_launch(void* const* d_in, const int* in_sizes, int n_in,
                              void* d_out, int out_size, void* d_ws, size_t ws_size,
                              hipStream_t stream) {
  const float* hs   = (const float*)d_in[0];
  const float* ip   = (const float*)d_in[1];
  const float* snp  = (const float*)d_in[2];
  const float* csp  = (const float*)d_in[3];
  const float* Wq   = (const float*)d_in[4];
  const float* bq   = (const float*)d_in[5];
  const float* Wk   = (const float*)d_in[6];
  const float* bk   = (const float*)d_in[7];
  const float* Wv   = (const float*)d_in[8];
  const float* bv   = (const float*)d_in[9];
  const float* Wo   = (const float*)d_in[10];
  const float* bo   = (const float*)d_in[11];
  const float* Wkip = (const float*)d_in[12];
  const float* bkip = (const float*)d_in[13];
  const float* Wvip = (const float*)d_in[14];
  const float* bvip = (const float*)d_in[15];
  const float* qs   = (const float*)d_in[16];
  const float* ks   = (const float*)d_in[17];
  float* out = (float*)d_out;

  // sizes (f16 elements)
  const long n1   = 6291456;   // 2048*3072
  const long nip  = 589824;    // 512*1152

  // static layout with lifetime-checked reuse (offsets unchanged from the
  // proven layout; weight regions now unused but reused for Opart buffers)
  const long o_hs   = 0;
  const long o_Wq   = 6291456;
  const long o_Wkip = 44630016;
  const long o_ip   = 44040192;
  const long o_q    = 51707904;
  const long o_k    = 57999360;
  const long o_v    = 64290816;
  const long o_kip  = 70582272;
  const long o_vip  = 72155136;
  const long o_qrot = 73728000;
  const long o_qnorm= 80019456;
  const long o_Vpip = 87883776;
  const long o_ml   = 89456640;   // float2[6*24*2048]
  const long o_Kps  = o_hs;
  const long o_Op0  = o_Wq;       // p0..p3 stride n1
  const long o_Op4  = o_Wkip;
  const long o_Op5  = o_q;
  const long o_Vps  = o_k;
  const long o_Kpip = o_kip;
  const long o_attn = o_v;

  f16* WS = (f16*)d_ws;
  auto P = [&](long off) { return WS + off; };
  float2* mlp = (float2*)(WS + o_ml);

  // 1) cast only hs + ip (weights consumed fp32 by the GEMMs)
  const long total4 = (n1 + nip) / 4;
  k_cvt2<<<dim3((total4 + 255) / 256), 256, 0, stream>>>(
      hs, P(o_hs), n1 / 4, ip, P(o_ip), total4);

  // 2) merged projections (QKV + ip in one launch; B = fp32 weights direct)
  ProjArgs pa;
  pa.A0 = P(o_hs); pa.A1 = P(o_ip);
  pa.Wq = Wq; pa.Wk = Wk; pa.Wv = Wv;
  pa.Wkip = Wkip; pa.Wvip = Wvip;
  pa.bq = bq; pa.bk = bk; pa.bv = bv; pa.bkip = bkip; pa.bvip = bvip;
  pa.q = P(o_q); pa.k = P(o_k); pa.v = P(o_v);
  pa.kip = P(o_kip); pa.vip = P(o_vip);
  k_gemm_proj<<<dim3(24, 16, 5), 256, 0, stream>>>(pa);

  // 3) prep (fused): qprep, krope_pack, rms_pack(ip), vpacks
  k_qprep<<<dim3(49152 / 4), 256, 0, stream>>>(P(o_q), snp, csp, qs, P(o_qrot), P(o_qnorm), 49152);
  k_krope_pack<<<dim3(786432 / 256), 256, 0, stream>>>(P(o_k), snp, csp, P(o_Kps), 2048, 786432);
  k_rms_pack<<<dim3(12288 / 16), 256, 0, stream>>>(P(o_kip), ks, P(o_Kpip), 512, 12288);
  k_vpack<<<dim3(32, 24), 256, 0, stream>>>(P(o_v),   P(o_Vps),  2048);
  k_vpack<<<dim3(8, 24),  256, 0, stream>>>(P(o_vip), P(o_Vpip), 512);

  // 4) flash with split-T (self: 4 splits of 512; ip: 2 splits of 256)
  k_flash2<<<dim3(16, 24, 4), 256, 0, stream>>>(P(o_qrot), P(o_Kps), P(o_Vps),
      P(o_Op0), n1, mlp, 0, 2048, 512);
  k_flash2<<<dim3(16, 24, 2), 256, 0, stream>>>(P(o_qnorm), P(o_Kpip), P(o_Vpip),
      P(o_Op4), o_Op5 - o_Op4, mlp, 4, 512, 256);

  // 5) combine partials -> attn (f16)
  k_combine<<<dim3(786432 / 256), 256, 0, stream>>>(
      P(o_Op0), P(o_Op0 + n1), P(o_Op0 + 2 * n1), P(o_Op0 + 3 * n1),
      P(o_Op4), P(o_Op5), mlp, P(o_attn), 786432);

  // 6) output projection -> fp32 d_out (B = Wo fp32 direct)
  k_gemm_nt<<<dim3(24, 16, 1), 256, 0, stream>>>(P(o_attn),
      Wo, bo, out, 2048, 3072, 3072);
}